// Round 10
// baseline (386.669 us; speedup 1.0000x reference)
//
#include <hip/hip_runtime.h>
#include <hip/hip_bf16.h>

// Inputs fp32, outputs fp32. Internal bf16 MFMA pipeline.
// R16: single mega-kernel, plain launch + atomic grid barrier (R13 lesson:
// hipLaunchCooperativeKernel silently no-ops under graph capture). Grid 512,
// 64 KB static LDS -> exactly 2 blocks/CU -> all 512 blocks co-resident by
// construction -> sense-reversing spin barrier cannot deadlock. Phases are
// the VERBATIM R15 kernel bodies: wt -> barrier -> qkv -> barrier -> fattn
// (two-pass in-block flash attention). Flags (cnt,gen) zeroed by an 8-B
// memset captured in the graph (reset every replay). Purpose: kill the two
// dispatch boundaries AND finally surface our counters (the ~140us fused
// dispatch tops the 80us fillBuffer curtain for the first time).

typedef __attribute__((ext_vector_type(8))) short bf16x8;
typedef __attribute__((ext_vector_type(4))) float f32x4;

#define NB 8
#define NT 2048
#define NC 1024
#define NH 64
#define NBLK 512

#define VM_DRAIN() asm volatile("s_waitcnt vmcnt(0)" ::: "memory")

__device__ __forceinline__ unsigned short f2bf(float f) {
    unsigned int u = __builtin_bit_cast(unsigned int, f);
    u += 0x7fffu + ((u >> 16) & 1u);   // RNE
    return (unsigned short)(u >> 16);
}

__device__ __forceinline__ bf16x8 cvt8(float4 a, float4 b) {
    union { bf16x8 v; __hip_bfloat162 h[4]; } u;
    u.h[0] = __float22bfloat162_rn(make_float2(a.x, a.y));
    u.h[1] = __float22bfloat162_rn(make_float2(a.z, a.w));
    u.h[2] = __float22bfloat162_rn(make_float2(b.x, b.y));
    u.h[3] = __float22bfloat162_rn(make_float2(b.z, b.w));
    return u.v;
}

// async 16B global->LDS; lds ptr must be wave-uniform (HW adds lane*16).
__device__ __forceinline__ void async_ld16(const void* g, const void* l) {
    __builtin_amdgcn_global_load_lds(
        (const __attribute__((address_space(1))) unsigned int*)g,
        (__attribute__((address_space(3))) unsigned int*)(unsigned int)(unsigned long long)l,
        16, 0, 0);
}

// Sense-reversing grid barrier. Safe iff all NBLK blocks co-resident
// (grid 512 = 2 blocks/CU x 256 CUs, enforced by 64 KB LDS).
__device__ __forceinline__ void grid_barrier(unsigned* cnt, unsigned* gen, int tid) {
    __syncthreads();
    if (tid == 0) {
        __threadfence();                       // agent-scope release
        unsigned g = __hip_atomic_load(gen, __ATOMIC_ACQUIRE, __HIP_MEMORY_SCOPE_AGENT);
        unsigned a = __hip_atomic_fetch_add(cnt, 1u, __ATOMIC_ACQ_REL, __HIP_MEMORY_SCOPE_AGENT);
        if (a == NBLK - 1u) {
            __hip_atomic_store(cnt, 0u, __ATOMIC_RELAXED, __HIP_MEMORY_SCOPE_AGENT);
            __hip_atomic_fetch_add(gen, 1u, __ATOMIC_RELEASE, __HIP_MEMORY_SCOPE_AGENT);
        } else {
            while (__hip_atomic_load(gen, __ATOMIC_ACQUIRE, __HIP_MEMORY_SCOPE_AGENT) == g)
                __builtin_amdgcn_s_sleep(2);
        }
        __threadfence();                       // agent-scope acquire
    }
    __syncthreads();
}

__global__ __launch_bounds__(256) void mega_kernel(
        const float* __restrict__ x,
        const float* __restrict__ Wq,
        const float* __restrict__ Wk,
        const float* __restrict__ Wv,
        unsigned short* __restrict__ Wt,
        unsigned short* __restrict__ qkv,
        unsigned short* __restrict__ v_t,
        float* __restrict__ res,
        float* __restrict__ attn,
        unsigned* __restrict__ flags) {
    __shared__ __align__(16) char smem[65536];   // 64 KB -> 2 blocks/CU

    int bx   = blockIdx.x;
    int tid  = threadIdx.x;
    int wave = tid >> 6, lane = tid & 63, quad = lane >> 4, l15 = lane & 15;
    unsigned* cnt = flags;
    unsigned* gen = flags + 1;

    // ================= phase 0: wt transpose (blocks 0..47) =============
    if (bx < 48) {
        float* tile = (float*)smem;            // [64][65]
        int m  = bx >> 4;
        int k0 = (bx & 15) * 64;
        const float* W = (m == 0) ? Wq : ((m == 1) ? Wk : Wv);
        for (int i = 0; i < 4; ++i) {
            int f = tid + i * 256;
            int r = f >> 4, c4 = (f & 15) * 4;
            float4 v = *(const float4*)&W[(size_t)(k0 + r) * 64 + c4];
            tile[r * 65 + c4 + 0] = v.x; tile[r * 65 + c4 + 1] = v.y;
            tile[r * 65 + c4 + 2] = v.z; tile[r * 65 + c4 + 3] = v.w;
        }
        __syncthreads();
        int n  = tid & 63;
        int kq = (tid >> 6) * 16;
        float scale = (m == 0) ? 0.03125f : 1.0f;
        __attribute__((aligned(16))) unsigned short outv[16];
        for (int j = 0; j < 16; ++j)
            outv[j] = f2bf(tile[(kq + j) * 65 + n] * scale);
        unsigned short* dst = &Wt[(size_t)m * (64 * 1024) + (size_t)n * 1024 + k0 + kq];
        *(uint4*)dst       = *(const uint4*)&outv[0];
        *(uint4*)(dst + 8) = *(const uint4*)&outv[8];
    }
    grid_barrier(cnt, gen, tid);

    // ================= phase 1: qkv GEMM (R15 body, verbatim) ===========
    {
        int row0 = bx * 32;

        f32x4 acc[2][3];
#pragma unroll
        for (int rt = 0; rt < 2; ++rt)
#pragma unroll
            for (int j = 0; j < 3; ++j) acc[rt][j] = (f32x4){0.f, 0.f, 0.f, 0.f};

        // prologue: stage kb=0 into buf0
#pragma unroll
        for (int i = 0; i < 2; ++i) {          // A: 32 rows x 256 B
            int s = i * 256 + tid;
            int m = s >> 4, p = s & 15;
            int j = (p & 8) | ((p & 7) ^ (m & 7));
            async_ld16(x + (size_t)(row0 + m) * NC + j * 4,
                       smem + i * 4096 + wave * 1024);
        }
#pragma unroll
        for (int i = 0; i < 6; ++i) {          // B: 192 rows x 128 B
            int s = i * 256 + tid;
            int n = s >> 3, p = s & 7;
            int j = p ^ (n & 7);
            async_ld16(Wt + (size_t)n * NC + j * 8,
                       smem + 8192 + i * 4096 + wave * 1024);
        }

        int cur = 0;
        for (int kb = 0; kb < 16; ++kb) {
            VM_DRAIN();                        // prev prefetch landed in LDS
            __syncthreads();                   // buf[cur] ready for all waves
            if (kb < 15) {                     // prefetch kb+1 -> buf[cur^1]
                char* nb = smem + (cur ^ 1) * 32768;
#pragma unroll
                for (int i = 0; i < 2; ++i) {
                    int s = i * 256 + tid;
                    int m = s >> 4, p = s & 15;
                    int j = (p & 8) | ((p & 7) ^ (m & 7));
                    async_ld16(x + (size_t)(row0 + m) * NC + (kb + 1) * 64 + j * 4,
                               nb + i * 4096 + wave * 1024);
                }
#pragma unroll
                for (int i = 0; i < 6; ++i) {
                    int s = i * 256 + tid;
                    int n = s >> 3, p = s & 7;
                    int j = p ^ (n & 7);
                    async_ld16(Wt + (size_t)n * NC + (kb + 1) * 64 + j * 8,
                               nb + 8192 + i * 4096 + wave * 1024);
                }
            }
            char* Ab = smem + cur * 32768;
            char* Bb = Ab + 8192;
#pragma unroll
            for (int c = 0; c < 2; ++c) {
                bf16x8 af[2];
#pragma unroll
                for (int rt = 0; rt < 2; ++rt) {
                    int m  = rt * 16 + l15;
                    int j0 = c * 8 + quad * 2;
                    int p0 = (j0 & 8) | ((j0 & 7) ^ (m & 7));
                    int p1 = (j0 & 8) | (((j0 + 1) & 7) ^ (m & 7));
                    float4 a0 = *(const float4*)(Ab + m * 256 + p0 * 16);
                    float4 a1 = *(const float4*)(Ab + m * 256 + p1 * 16);
                    af[rt] = cvt8(a0, a1);
                }
#pragma unroll
                for (int jj = 0; jj < 3; ++jj) {
                    int n = (wave * 3 + jj) * 16 + l15;
                    int p = (c * 4 + quad) ^ (n & 7);
                    bf16x8 bf = *(const bf16x8*)(Bb + n * 128 + p * 16);
#pragma unroll
                    for (int rt = 0; rt < 2; ++rt)
                        acc[rt][jj] = __builtin_amdgcn_mfma_f32_16x16x32_bf16(
                            af[rt], bf, acc[rt][jj], 0, 0, 0);
                }
            }
            cur ^= 1;
        }

        int b = row0 >> 11;
#pragma unroll
        for (int jj = 0; jj < 3; ++jj) {
            int g   = wave * 3 + jj;
            int mat = g >> 2;
            int col = (g & 3) * 16 + l15;
#pragma unroll
            for (int rt = 0; rt < 2; ++rt) {
                int rowb = row0 + rt * 16 + quad * 4;
                if (mat < 2) {
#pragma unroll
                    for (int r = 0; r < 4; ++r)
                        qkv[(size_t)mat * (16384 * 64) + (size_t)(rowb + r) * 64 + col] =
                            f2bf(acc[rt][jj][r]);
                } else {
                    union { unsigned long long q; unsigned short us[4]; } pk;
#pragma unroll
                    for (int r = 0; r < 4; ++r) pk.us[r] = f2bf(acc[rt][jj][r]);
                    *(unsigned long long*)&v_t[((size_t)b * 64 + col) * NT + (rowb & 2047)] = pk.q;
                }
            }
        }
    }
    grid_barrier(cnt, gen, tid);

    // ================= phase 2: fattn two-pass (R15 body) ===============
    {
        const unsigned short* qg  = qkv;
        const unsigned short* kg  = qkv + 16384 * 64;
        const unsigned short* vtg = v_t;

        char*  ktb    = smem;                  // 2 x 8 KB, K dbuf
        char*  vtb    = smem + 16384;          // 2 x 8 KB, V^T dbuf
        float* ptf    = (float*)(smem + 32768);   // 32 x 68 fp32
        float* rsred  = (float*)(smem + 41472);   // [2][32]
        float* rinv_s = (float*)(smem + 41728);   // [32]

        int gx  = bx & 63;
        int b   = bx >> 6;
        int rsp = gx & 1;
        int j   = gx >> 1;
        int it  = (b & 4) ? (31 - j) : j;      // complementary pairing
        int wr = wave & 1, wc = wave >> 1;
        int tb = it * 64 + rsp * 32;
        size_t brow = (size_t)b * NT;

        bf16x8 qf[2];
        {
            const unsigned short* qp = qg + (brow + tb + wr * 16 + l15) * NH + quad * 8;
            qf[0] = *(const bf16x8*)qp;
            qf[1] = *(const bf16x8*)(qp + 32);
        }
        int trow[4];
#pragma unroll
        for (int r = 0; r < 4; ++r) trow[r] = tb + wr * 16 + quad * 4 + r;

        float rs[4] = {0.f, 0.f, 0.f, 0.f};

        // ---- PASS 1: rowsums (K staging only) ----
#pragma unroll
        for (int i = 0; i < 2; ++i) {
            int s = i * 256 + tid;
            int r = s >> 3, p = s & 7;
            int jj = p ^ (r & 7);
            async_ld16(kg + (brow + r) * NH + jj * 8,
                       ktb + i * 4096 + wave * 1024);
        }
        int cur = 0;
        for (int st = 0; st <= it; ++st) {
            VM_DRAIN();
            __syncthreads();
            if (st + 1 <= it) {
#pragma unroll
                for (int i = 0; i < 2; ++i) {
                    int s = i * 256 + tid;
                    int r = s >> 3, p = s & 7;
                    int jj = p ^ (r & 7);
                    async_ld16(kg + (brow + (st + 1) * 64 + r) * NH + jj * 8,
                               ktb + (cur ^ 1) * 8192 + i * 4096 + wave * 1024);
                }
            }
            char* kb = ktb + cur * 8192;

            f32x4 sacc[2];
            sacc[0] = (f32x4){0.f, 0.f, 0.f, 0.f};
            sacc[1] = (f32x4){0.f, 0.f, 0.f, 0.f};
#pragma unroll
            for (int c = 0; c < 2; ++c)
#pragma unroll
                for (int ntl = 0; ntl < 2; ++ntl) {
                    int n = wc * 32 + ntl * 16 + l15;
                    int p = (c * 4 + quad) ^ (n & 7);
                    bf16x8 kf = *(const bf16x8*)(kb + n * 128 + p * 16);
                    sacc[ntl] = __builtin_amdgcn_mfma_f32_16x16x32_bf16(
                        qf[c], kf, sacc[ntl], 0, 0, 0);
                }
            bool dia = (st == it);
#pragma unroll
            for (int ntl = 0; ntl < 2; ++ntl) {
                int s_g = st * 64 + wc * 32 + ntl * 16 + l15;
#pragma unroll
                for (int r = 0; r < 4; ++r) {
                    float e = __expf(sacc[ntl][r]);
                    if (dia && s_g > trow[r]) e = 0.f;
                    rs[r] += e;
                }
            }
            cur ^= 1;
        }

        // block-local rowsum reduce -> rinv
#pragma unroll
        for (int r = 0; r < 4; ++r) {
            float v = rs[r];
            v += __shfl_xor(v, 1, 16);
            v += __shfl_xor(v, 2, 16);
            v += __shfl_xor(v, 4, 16);
            v += __shfl_xor(v, 8, 16);
            if (l15 == 0) rsred[wc * 32 + wr * 16 + quad * 4 + r] = v;
        }
        __syncthreads();
        if (tid < 32) rinv_s[tid] = 1.0f / (rsred[tid] + rsred[32 + tid]);
        __syncthreads();
        float rinv[4];
#pragma unroll
        for (int r = 0; r < 4; ++r) rinv[r] = rinv_s[wr * 16 + quad * 4 + r];

        // ---- PASS 2: normalized stores + PV ----
#pragma unroll
        for (int i = 0; i < 2; ++i) {
            int s = i * 256 + tid;
            int r = s >> 3, p = s & 7;
            int jj = p ^ (r & 7);
            async_ld16(kg + (brow + r) * NH + jj * 8,
                       ktb + i * 4096 + wave * 1024);
            async_ld16(vtg + ((size_t)b * 64 + r) * NT + jj * 8,
                       vtb + i * 4096 + wave * 1024);
        }
        cur = 0;
        f32x4 oacc[2];
        oacc[0] = (f32x4){0.f, 0.f, 0.f, 0.f};
        oacc[1] = (f32x4){0.f, 0.f, 0.f, 0.f};

        for (int st = 0; st <= it; ++st) {
            VM_DRAIN();
            __syncthreads();
            if (st + 1 <= it) {
#pragma unroll
                for (int i = 0; i < 2; ++i) {
                    int s = i * 256 + tid;
                    int r = s >> 3, p = s & 7;
                    int jj = p ^ (r & 7);
                    async_ld16(kg + (brow + (st + 1) * 64 + r) * NH + jj * 8,
                               ktb + (cur ^ 1) * 8192 + i * 4096 + wave * 1024);
                    async_ld16(vtg + ((size_t)b * 64 + r) * NT + (st + 1) * 64 + jj * 8,
                               vtb + (cur ^ 1) * 8192 + i * 4096 + wave * 1024);
                }
            }
            char* kb = ktb + cur * 8192;
            char* vb = vtb + cur * 8192;

            f32x4 sacc[2];
            sacc[0] = (f32x4){0.f, 0.f, 0.f, 0.f};
            sacc[1] = (f32x4){0.f, 0.f, 0.f, 0.f};
#pragma unroll
            for (int c = 0; c < 2; ++c)
#pragma unroll
                for (int ntl = 0; ntl < 2; ++ntl) {
                    int n = wc * 32 + ntl * 16 + l15;
                    int p = (c * 4 + quad) ^ (n & 7);
                    bf16x8 kf = *(const bf16x8*)(kb + n * 128 + p * 16);
                    sacc[ntl] = __builtin_amdgcn_mfma_f32_16x16x32_bf16(
                        qf[c], kf, sacc[ntl], 0, 0, 0);
                }

            bool dia = (st == it);
#pragma unroll
            for (int ntl = 0; ntl < 2; ++ntl) {
                int s_g = st * 64 + wc * 32 + ntl * 16 + l15;
#pragma unroll
                for (int r = 0; r < 4; ++r) {
                    float p = __expf(sacc[ntl][r]) * rinv[r];
                    if (dia && s_g > trow[r]) p = 0.f;
                    ptf[(wr * 16 + quad * 4 + r) * 68 + wc * 32 + ntl * 16 + l15] = p;
                }
            }
            __syncthreads();                   // ptf complete (cross-wave)

            // normalized attn store: 32 rows x 256 B, coalesced float4
#pragma unroll
            for (int k = 0; k < 2; ++k) {
                int f = k * 256 + tid;
                int row = f >> 4, c4 = (f & 15) * 4;
                *(float4*)&attn[(brow + tb + row) * NT + st * 64 + c4] =
                    *(const float4*)&ptf[row * 68 + c4];
            }
            // mirror-zero upper tile (st, it) rows rsp*32..+32
            if (st < it) {
                float4 z4 = {0.f, 0.f, 0.f, 0.f};
#pragma unroll
                for (int k = 0; k < 2; ++k) {
                    int f = k * 256 + tid;
                    int row = f >> 4, c4 = (f & 15) * 4;
                    *(float4*)&attn[(brow + st * 64 + rsp * 32 + row) * NT + it * 64 + c4] = z4;
                }
            }

            // PV (normalized)
#pragma unroll
            for (int c = 0; c < 2; ++c) {
                const float* pp = &ptf[(wr * 16 + l15) * 68 + c * 32 + quad * 8];
                float4 a0 = *(const float4*)pp;
                float4 a1 = *(const float4*)(pp + 4);
                bf16x8 pf = cvt8(a0, a1);
#pragma unroll
                for (int ntl = 0; ntl < 2; ++ntl) {
                    int n = wc * 32 + ntl * 16 + l15;
                    int p = (c * 4 + quad) ^ (n & 7);
                    bf16x8 vf = *(const bf16x8*)(vb + n * 128 + p * 16);
                    oacc[ntl] = __builtin_amdgcn_mfma_f32_16x16x32_bf16(
                        pf, vf, oacc[ntl], 0, 0, 0);
                }
            }
            cur ^= 1;
        }

        // res: direct store
#pragma unroll
        for (int ntl = 0; ntl < 2; ++ntl)
#pragma unroll
            for (int r = 0; r < 4; ++r)
                res[(size_t)(brow + trow[r]) * NH + wc * 32 + ntl * 16 + l15] = oacc[ntl][r];
    }
}

// ---------------------------------------------------------------------------
extern "C" void kernel_launch(void* const* d_in, const int* in_sizes, int n_in,
                              void* d_out, int out_size, void* d_ws, size_t ws_size,
                              hipStream_t stream) {
    const float* x  = (const float*)d_in[0];
    const float* Wq = (const float*)d_in[1];
    const float* Wk = (const float*)d_in[2];
    const float* Wv = (const float*)d_in[3];

    unsigned short* ws  = (unsigned short*)d_ws;
    unsigned short* Wt  = ws;                          // 3*64*1024 bf16
    unsigned short* qkv = ws + 3 * 64 * 1024;          // 2*16384*64 bf16 (q,k)
    unsigned short* v_t = qkv + 2 * 16384 * 64;        // 16384*64 bf16 [b][h][t]
    unsigned* flags = (unsigned*)(v_t + 16384 * 64);   // cnt, gen

    float* res  = (float*)d_out;                       // [8,2048,64]
    float* attn = res + (size_t)NB * NT * NH;          // [8,2048,2048]

    hipMemsetAsync(flags, 0, 2 * sizeof(unsigned), stream);

    void* kargs[] = {(void*)&x, (void*)&Wq, (void*)&Wk, (void*)&Wv, (void*)&Wt,
                     (void*)&qkv, (void*)&v_t, (void*)&res, (void*)&attn,
                     (void*)&flags};
    hipLaunchKernelGGL(mega_kernel, dim3(NBLK), dim3(256), 0, stream,
                       x, Wq, Wk, Wv, Wt, qkv, v_t, res, attn, flags);
    (void)kargs;
}